// Round 1
// baseline (293.101 us; speedup 1.0000x reference)
//
#include <hip/hip_runtime.h>

// ---------------------------------------------------------------------------
// TripletContrastiveLoss on MI355X (gfx950)
// B=8192, D=1024 fp32 features; labels/domain int; scalar fp32 output.
//
// Pipeline:
//   memset(posmin/negmin = 0xFF, counters = 0)
//   k1: normalize rows -> bf16, compact anchors(front)/fields(back) into G
//   k2: 128x128 MFMA tiles of A·F^T -> d = sqrt(|a|^2+|f|^2-2ab) -> atomicMin
//   k3: hinge + sum/count reduction
//   k4: scalar finalize
// ---------------------------------------------------------------------------

#define B_ROWS 8192
#define DIM    1024

typedef __bf16 bf16x8 __attribute__((ext_vector_type(8)));
typedef float  f32x4  __attribute__((ext_vector_type(4)));

__device__ __forceinline__ unsigned short f2bf_rne(float x) {
    unsigned u = __float_as_uint(x);
    unsigned r = (u + 0x7FFFu + ((u >> 16) & 1u)) >> 16;
    return (unsigned short)r;
}
__device__ __forceinline__ float bf2f(unsigned short h) {
    return __uint_as_float(((unsigned)h) << 16);
}

// ---------------------------------------------------------------------------
// Kernel 1: per-row L2 normalize (fp32), round to bf16, compact by domain.
// Anchors (domain==0) take slots [0, nA) from the front; fields (domain==1)
// take slots from the back. nA + nF == B_ROWS, so fields occupy [nA, 8192).
// sqG[slot] = sum of squares of the *bf16-rounded* row (fp32 accum) so the
// distance formula is self-consistent with the MFMA dot products.
// ---------------------------------------------------------------------------
__global__ __launch_bounds__(256) void normalize_compact(
    const float* __restrict__ feat, const int* __restrict__ labels,
    const int* __restrict__ dom, unsigned short* __restrict__ G,
    int* __restrict__ labG, float* __restrict__ sqG, unsigned* __restrict__ cnt)
{
    const int row = blockIdx.x;
    const int t = threadIdx.x;
    const int lane = t & 63, w = t >> 6;
    __shared__ float sbuf[4];
    __shared__ int slot_s;

    const float4 v = ((const float4*)(feat + (size_t)row * DIM))[t];
    float ss = v.x * v.x + v.y * v.y + v.z * v.z + v.w * v.w;
    #pragma unroll
    for (int s = 32; s > 0; s >>= 1) ss += __shfl_down(ss, s);
    if (lane == 0) sbuf[w] = ss;
    __syncthreads();
    const float total = sbuf[0] + sbuf[1] + sbuf[2] + sbuf[3];
    const float inv = 1.0f / fmaxf(sqrtf(total), 1e-12f);

    float fv[4] = {v.x * inv, v.y * inv, v.z * inv, v.w * inv};
    unsigned short ub[4];
    float ss2 = 0.0f;
    #pragma unroll
    for (int i = 0; i < 4; ++i) {
        ub[i] = f2bf_rne(fv[i]);
        const float fr = bf2f(ub[i]);
        ss2 += fr * fr;
    }
    __syncthreads();  // sbuf reuse
    #pragma unroll
    for (int s = 32; s > 0; s >>= 1) ss2 += __shfl_down(ss2, s);
    if (lane == 0) sbuf[w] = ss2;
    __syncthreads();

    if (t == 0) {
        int slot;
        if (dom[row] == 0) slot = (int)atomicAdd(&cnt[0], 1u);
        else               slot = (B_ROWS - 1) - (int)atomicAdd(&cnt[1], 1u);
        labG[slot] = labels[row];
        sqG[slot]  = sbuf[0] + sbuf[1] + sbuf[2] + sbuf[3];
        slot_s = slot;
    }
    __syncthreads();
    const int slot = slot_s;
    ushort4 pk; pk.x = ub[0]; pk.y = ub[1]; pk.z = ub[2]; pk.w = ub[3];
    ((ushort4*)(G + (size_t)slot * DIM))[t] = pk;
}

// ---------------------------------------------------------------------------
// Kernel 2: 128x128 distance tile. 4 waves, each computes a 64x64 sub-tile
// via 4x4 grid of 16x16x32 bf16 MFMAs over K=1024 (32 K-steps).
// LDS row stride 40 shorts (= 80 B, 16B-aligned, 2-way bank alias = free).
// Epilogue: dot -> distance, pos/neg min per anchor row, atomicMin (uint
// ordering valid since d >= 0).
// ---------------------------------------------------------------------------
__global__ __launch_bounds__(256) void tile_mindist(
    const unsigned short* __restrict__ G, const int* __restrict__ labG,
    const float* __restrict__ sqG, const unsigned* __restrict__ cnt,
    unsigned* __restrict__ posmin, unsigned* __restrict__ negmin)
{
    const int nA = (int)cnt[0];
    const int rowA0 = blockIdx.x * 128;
    const int rowF0 = nA + blockIdx.y * 128;
    if (rowA0 >= nA || rowF0 >= B_ROWS) return;

    __shared__ __align__(16) unsigned short As[128 * 40];
    __shared__ __align__(16) unsigned short Fs[128 * 40];

    const int t = threadIdx.x;
    const int lane = t & 63, w = t >> 6;
    const int wm = w >> 1, wn = w & 1;     // wave sub-tile (rows, cols) * 64
    const int l15 = lane & 15, quad = lane >> 4;

    f32x4 acc[4][4] = {};

    for (int kk = 0; kk < DIM; kk += 32) {
        __syncthreads();
        #pragma unroll
        for (int h = 0; h < 2; ++h) {
            const int q = t + h * 256;          // 512 chunks of 8 bf16
            const int r = q >> 2, c = (q & 3) * 8;
            const uint4 va = *(const uint4*)(G + (size_t)(rowA0 + r) * DIM + kk + c);
            *(uint4*)(&As[r * 40 + c]) = va;
            int rf = rowF0 + r; rf = rf > (B_ROWS - 1) ? (B_ROWS - 1) : rf;
            const uint4 vf = *(const uint4*)(G + (size_t)rf * DIM + kk + c);
            *(uint4*)(&Fs[r * 40 + c]) = vf;
        }
        __syncthreads();

        bf16x8 a[4], b[4];
        #pragma unroll
        for (int fm = 0; fm < 4; ++fm)
            a[fm] = *(const bf16x8*)(&As[(wm * 64 + fm * 16 + l15) * 40 + quad * 8]);
        #pragma unroll
        for (int fn = 0; fn < 4; ++fn)
            b[fn] = *(const bf16x8*)(&Fs[(wn * 64 + fn * 16 + l15) * 40 + quad * 8]);
        #pragma unroll
        for (int fm = 0; fm < 4; ++fm)
            #pragma unroll
            for (int fn = 0; fn < 4; ++fn)
                acc[fm][fn] = __builtin_amdgcn_mfma_f32_16x16x32_bf16(
                    a[fm], b[fn], acc[fm][fn], 0, 0, 0);
    }

    // Epilogue. C/D layout: col = lane&15 (field), row = quad*4 + reg (anchor).
    const float INFV = __uint_as_float(0x7f800000u);
    float sqf[4]; int lf[4]; bool vf[4];
    #pragma unroll
    for (int fn = 0; fn < 4; ++fn) {
        const int rf = rowF0 + wn * 64 + fn * 16 + l15;
        vf[fn] = rf < B_ROWS;
        const int rc = vf[fn] ? rf : (B_ROWS - 1);
        sqf[fn] = sqG[rc];
        lf[fn]  = labG[rc];
    }
    #pragma unroll
    for (int fm = 0; fm < 4; ++fm) {
        #pragma unroll
        for (int r = 0; r < 4; ++r) {
            const int ra = rowA0 + wm * 64 + fm * 16 + quad * 4 + r;
            const bool va = ra < nA;
            const int rac = va ? ra : 0;
            const float sqa = sqG[rac];
            const int la = labG[rac];
            float pmin = INFV, nmin = INFV;
            #pragma unroll
            for (int fn = 0; fn < 4; ++fn) {
                const float dot = acc[fm][fn][r];
                const float d = sqrtf(fmaxf(sqa + sqf[fn] - 2.0f * dot, 0.0f));
                if (vf[fn]) {
                    if (la == lf[fn]) pmin = fminf(pmin, d);
                    else              nmin = fminf(nmin, d);
                }
            }
            #pragma unroll
            for (int s = 1; s < 16; s <<= 1) {
                pmin = fminf(pmin, __shfl_xor(pmin, s));
                nmin = fminf(nmin, __shfl_xor(nmin, s));
            }
            if (l15 == 0 && va) {
                if (pmin < INFV) atomicMin(&posmin[ra], __float_as_uint(pmin));
                if (nmin < INFV) atomicMin(&negmin[ra], __float_as_uint(nmin));
            }
        }
    }
}

// ---------------------------------------------------------------------------
// Kernel 3: hinge + sum/count. Slots >= nA were never touched (stay 0xFF...)
// and naturally drop out as invalid.
// ---------------------------------------------------------------------------
__global__ __launch_bounds__(256) void reduce_loss(
    const unsigned* __restrict__ posmin, const unsigned* __restrict__ negmin,
    float* __restrict__ accum)
{
    const int i = blockIdx.x * 256 + threadIdx.x;
    const unsigned up = posmin[i], un = negmin[i];
    float tl = 0.0f, c = 0.0f;
    if (up != 0xFFFFFFFFu && un != 0xFFFFFFFFu) {
        tl = fmaxf(__uint_as_float(up) - __uint_as_float(un) + 0.3f, 0.0f);
        c = 1.0f;
    }
    #pragma unroll
    for (int s = 32; s > 0; s >>= 1) {
        tl += __shfl_down(tl, s);
        c  += __shfl_down(c, s);
    }
    __shared__ float sb[8];
    const int lane = threadIdx.x & 63, w = threadIdx.x >> 6;
    if (lane == 0) { sb[w] = tl; sb[4 + w] = c; }
    __syncthreads();
    if (threadIdx.x == 0) {
        atomicAdd(&accum[0], sb[0] + sb[1] + sb[2] + sb[3]);
        atomicAdd(&accum[1], sb[4] + sb[5] + sb[6] + sb[7]);
    }
}

__global__ void finalize(const float* __restrict__ accum, float* __restrict__ out) {
    const float s = accum[0], c = accum[1];
    out[0] = (c > 0.0f) ? s / fmaxf(c, 1.0f) : 0.0f;
}

// ---------------------------------------------------------------------------
extern "C" void kernel_launch(void* const* d_in, const int* in_sizes, int n_in,
                              void* d_out, int out_size, void* d_ws, size_t ws_size,
                              hipStream_t stream) {
    const float* feat  = (const float*)d_in[0];
    const int* labels  = (const int*)d_in[1];
    const int* dom     = (const int*)d_in[2];
    float* out = (float*)d_out;

    char* ws = (char*)d_ws;
    // Workspace layout (bytes):
    unsigned short* G   = (unsigned short*)(ws);                 // 16,777,216
    int*      labG      = (int*)(ws + 16777216);                 //     32,768
    float*    sqG       = (float*)(ws + 16809984);               //     32,768
    unsigned* posmin    = (unsigned*)(ws + 16842752);            //     32,768
    unsigned* negmin    = (unsigned*)(ws + 16875520);            //     32,768
    unsigned* cnt       = (unsigned*)(ws + 16908288);            //  8 (cntA, cntF)
    float*    accum     = (float*)(ws + 16908296);               //  8 (sum, count)

    hipMemsetAsync(posmin, 0xFF, 65536, stream);   // posmin+negmin contiguous
    hipMemsetAsync(cnt, 0, 16, stream);            // counters + accum

    normalize_compact<<<B_ROWS, 256, 0, stream>>>(feat, labels, dom, G, labG, sqG, cnt);

    dim3 grid(B_ROWS / 128, B_ROWS / 128);         // inactive tiles early-exit
    tile_mindist<<<grid, 256, 0, stream>>>(G, labG, sqG, cnt, posmin, negmin);

    reduce_loss<<<B_ROWS / 256, 256, 0, stream>>>(posmin, negmin, accum);
    finalize<<<1, 1, 0, stream>>>(accum, out);
}

// Round 4
// 268.956 us; speedup vs baseline: 1.0898x; 1.0898x over previous
//
#include <hip/hip_runtime.h>

// ---------------------------------------------------------------------------
// TripletContrastiveLoss on MI355X (gfx950)  — Round 4
// Reverted global_load_lds (R2/R3 kernel correlated with container deaths);
// synchronous staging like the R1 kernel that ran clean, now software-
// pipelined: VGPR prefetch + double-buffered LDS + 1 barrier per K-step,
// persistent all-working grid, d^2-min epilogue.
// ---------------------------------------------------------------------------

#define B_ROWS 8192
#define DIM    1024

typedef __bf16 bf16x8 __attribute__((ext_vector_type(8)));
typedef float  f32x4  __attribute__((ext_vector_type(4)));

__device__ __forceinline__ unsigned short f2bf_rne(float x) {
    unsigned u = __float_as_uint(x);
    unsigned r = (u + 0x7FFFu + ((u >> 16) & 1u)) >> 16;
    return (unsigned short)r;
}
__device__ __forceinline__ float bf2f(unsigned short h) {
    return __uint_as_float(((unsigned)h) << 16);
}

// ---------------------------------------------------------------------------
// Kernel 1: per-row L2 normalize (fp32), round to bf16, compact by domain.
// Anchors (domain==0) -> slots [0,nA); fields fill from the back.
// sqG[slot] = sum of squares of the bf16-rounded row so the distance formula
// is self-consistent with the MFMA dot products. Also inits posmin/negmin.
// ---------------------------------------------------------------------------
__global__ __launch_bounds__(256) void normalize_compact(
    const float* __restrict__ feat, const int* __restrict__ labels,
    const int* __restrict__ dom, unsigned short* __restrict__ G,
    int* __restrict__ labG, float* __restrict__ sqG, unsigned* __restrict__ cnt,
    unsigned* __restrict__ posmin, unsigned* __restrict__ negmin)
{
    const int row = blockIdx.x;
    const int t = threadIdx.x;
    const int lane = t & 63, w = t >> 6;
    __shared__ float sbuf[4];
    __shared__ int slot_s;

    if (t == 0) { posmin[row] = 0xFFFFFFFFu; negmin[row] = 0xFFFFFFFFu; }

    const float4 v = ((const float4*)(feat + (size_t)row * DIM))[t];
    float ss = v.x * v.x + v.y * v.y + v.z * v.z + v.w * v.w;
    #pragma unroll
    for (int s = 32; s > 0; s >>= 1) ss += __shfl_down(ss, s);
    if (lane == 0) sbuf[w] = ss;
    __syncthreads();
    const float total = sbuf[0] + sbuf[1] + sbuf[2] + sbuf[3];
    const float inv = 1.0f / fmaxf(sqrtf(total), 1e-12f);

    float fv[4] = {v.x * inv, v.y * inv, v.z * inv, v.w * inv};
    unsigned short ub[4];
    float ss2 = 0.0f;
    #pragma unroll
    for (int i = 0; i < 4; ++i) {
        ub[i] = f2bf_rne(fv[i]);
        const float fr = bf2f(ub[i]);
        ss2 += fr * fr;
    }
    __syncthreads();  // sbuf reuse
    #pragma unroll
    for (int s = 32; s > 0; s >>= 1) ss2 += __shfl_down(ss2, s);
    if (lane == 0) sbuf[w] = ss2;
    __syncthreads();

    if (t == 0) {
        int slot;
        if (dom[row] == 0) slot = (int)atomicAdd(&cnt[0], 1u);
        else               slot = (B_ROWS - 1) - (int)atomicAdd(&cnt[1], 1u);
        labG[slot] = labels[row];
        sqG[slot]  = sbuf[0] + sbuf[1] + sbuf[2] + sbuf[3];
        slot_s = slot;
    }
    __syncthreads();
    const int slot = slot_s;
    ushort4 pk; pk.x = ub[0]; pk.y = ub[1]; pk.z = ub[2]; pk.w = ub[3];
    ((ushort4*)(G + (size_t)slot * DIM))[t] = pk;
}

// ---------------------------------------------------------------------------
// Kernel 2: persistent 128x128 tiles, 4 waves (each 64x64 via 4x4 of
// 16x16x32 bf16 MFMA), K=1024 in 32 steps. Double-buffered LDS (stride 40
// shorts), VGPR prefetch of step k+1 before the MFMAs of step k, ONE barrier
// per step. Epilogue: min d^2 per anchor row -> atomicMin (uint order).
// ---------------------------------------------------------------------------
__global__ __launch_bounds__(256) void tile_mindist(
    const unsigned short* __restrict__ G, const int* __restrict__ labG,
    const float* __restrict__ sqG, const unsigned* __restrict__ cnt,
    unsigned* __restrict__ posmin, unsigned* __restrict__ negmin)
{
    const int nA = (int)cnt[0];
    const int nF = B_ROWS - nA;
    const int nTA = (nA + 127) >> 7;
    const int nTF = (nF + 127) >> 7;
    const int total = nTA * nTF;

    // [buf][A=0/F=1][128 rows x 40 shorts]  = 40,960 B
    __shared__ __align__(16) unsigned short S[2][2][128 * 40];

    const int t = threadIdx.x;
    const int lane = t & 63, w = t >> 6;
    const int wm = w >> 1, wn = w & 1;          // wave sub-tile coords (x64)
    const int l15 = lane & 15, quad = lane >> 4;

    // Staging geometry: thread q (and q+256) fills row q>>2, 16-B chunk q&3.
    const int r0 = t >> 2;                       // rows r0 and r0+64
    const int cByte = (t & 3) * 16;              // byte col within 64-B K-chunk
    const int wOff0 = r0 * 40 + (cByte >> 1);    // LDS write offset (shorts)
    const int wOff1 = (r0 + 64) * 40 + (cByte >> 1);
    // Fragment read offsets (shorts)
    const int rdA = (wm * 64 + l15) * 40 + quad * 8;
    const int rdF = (wn * 64 + l15) * 40 + quad * 8;

    const char* Gb = (const char*)G;

    for (int tile = blockIdx.x; tile < total; tile += gridDim.x) {
        const int tx = tile % nTA;
        const int ty = tile / nTA;
        const int rowA0 = tx * 128;
        const int rowF0 = nA + ty * 128;

        int rF0c = rowF0 + r0;       if (rF0c > B_ROWS - 1) rF0c = B_ROWS - 1;
        int rF1c = rowF0 + r0 + 64;  if (rF1c > B_ROWS - 1) rF1c = B_ROWS - 1;
        const char* gA0 = Gb + (size_t)(rowA0 + r0) * (DIM * 2) + cByte;
        const char* gA1 = gA0 + (size_t)64 * (DIM * 2);
        const char* gF0 = Gb + (size_t)rF0c * (DIM * 2) + cByte;
        const char* gF1 = Gb + (size_t)rF1c * (DIM * 2) + cByte;

        f32x4 acc[4][4] = {};

        // Prologue: stage K-chunk 0 into buffer 0.
        {
            const uint4 a0 = *(const uint4*)(gA0);
            const uint4 a1 = *(const uint4*)(gA1);
            const uint4 f0 = *(const uint4*)(gF0);
            const uint4 f1 = *(const uint4*)(gF1);
            *(uint4*)&S[0][0][wOff0] = a0;
            *(uint4*)&S[0][0][wOff1] = a1;
            *(uint4*)&S[0][1][wOff0] = f0;
            *(uint4*)&S[0][1][wOff1] = f1;
        }
        __syncthreads();

        #pragma unroll 4
        for (int step = 0; step < 32; ++step) {
            const int cur = step & 1;
            const bool has_next = step < 31;
            uint4 na0, na1, nf0, nf1;
            if (has_next) {                       // prefetch K-chunk step+1
                const int off = (step + 1) * 64;
                na0 = *(const uint4*)(gA0 + off);
                na1 = *(const uint4*)(gA1 + off);
                nf0 = *(const uint4*)(gF0 + off);
                nf1 = *(const uint4*)(gF1 + off);
            }

            const unsigned short* pa = &S[cur][0][rdA];
            const unsigned short* pf = &S[cur][1][rdF];
            bf16x8 a[4], b[4];
            #pragma unroll
            for (int fm = 0; fm < 4; ++fm) a[fm] = *(const bf16x8*)(pa + fm * 640);
            #pragma unroll
            for (int fn = 0; fn < 4; ++fn) b[fn] = *(const bf16x8*)(pf + fn * 640);
            #pragma unroll
            for (int fm = 0; fm < 4; ++fm)
                #pragma unroll
                for (int fn = 0; fn < 4; ++fn)
                    acc[fm][fn] = __builtin_amdgcn_mfma_f32_16x16x32_bf16(
                        a[fm], b[fn], acc[fm][fn], 0, 0, 0);

            if (has_next) {                       // stage into the other buffer
                const int nb = cur ^ 1;
                *(uint4*)&S[nb][0][wOff0] = na0;
                *(uint4*)&S[nb][0][wOff1] = na1;
                *(uint4*)&S[nb][1][wOff0] = nf0;
                *(uint4*)&S[nb][1][wOff1] = nf1;
            }
            __syncthreads();                      // one barrier per step
        }

        // Epilogue. C/D layout: col = lane&15 (field), row = quad*4+reg (anchor).
        const float INFV = __uint_as_float(0x7f800000u);
        float sqf[4]; int lf_[4]; bool vf[4];
        #pragma unroll
        for (int fn = 0; fn < 4; ++fn) {
            const int rf = rowF0 + wn * 64 + fn * 16 + l15;
            vf[fn] = rf < B_ROWS;
            const int rc = vf[fn] ? rf : (B_ROWS - 1);
            sqf[fn] = sqG[rc];
            lf_[fn] = labG[rc];
        }
        #pragma unroll
        for (int fm = 0; fm < 4; ++fm) {
            #pragma unroll
            for (int r = 0; r < 4; ++r) {
                const int ra = rowA0 + wm * 64 + fm * 16 + quad * 4 + r;
                const bool va = ra < nA;
                const int rac = va ? ra : 0;
                const float sqa = sqG[rac];
                const int la_ = labG[rac];
                float pmin = INFV, nmin = INFV;
                #pragma unroll
                for (int fn = 0; fn < 4; ++fn) {
                    const float dd = fmaxf(sqa + sqf[fn] - 2.0f * acc[fm][fn][r], 0.0f);
                    if (vf[fn]) {
                        if (la_ == lf_[fn]) pmin = fminf(pmin, dd);
                        else                nmin = fminf(nmin, dd);
                    }
                }
                #pragma unroll
                for (int s = 1; s < 16; s <<= 1) {
                    pmin = fminf(pmin, __shfl_xor(pmin, s));
                    nmin = fminf(nmin, __shfl_xor(nmin, s));
                }
                if (l15 == 0 && va) {
                    if (pmin < INFV) atomicMin(&posmin[ra], __float_as_uint(pmin));
                    if (nmin < INFV) atomicMin(&negmin[ra], __float_as_uint(nmin));
                }
            }
        }
    }
}

// ---------------------------------------------------------------------------
// Kernel 3: sqrt(d^2 mins) + hinge + sum/count. Untouched slots stay
// 0xFFFFFFFF and drop out as invalid.
// ---------------------------------------------------------------------------
__global__ __launch_bounds__(256) void reduce_loss(
    const unsigned* __restrict__ posmin, const unsigned* __restrict__ negmin,
    float* __restrict__ accum)
{
    const int i = blockIdx.x * 256 + threadIdx.x;
    const unsigned up = posmin[i], un = negmin[i];
    float tl = 0.0f, c = 0.0f;
    if (up != 0xFFFFFFFFu && un != 0xFFFFFFFFu) {
        const float pd = sqrtf(__uint_as_float(up));
        const float nd = sqrtf(__uint_as_float(un));
        tl = fmaxf(pd - nd + 0.3f, 0.0f);
        c = 1.0f;
    }
    #pragma unroll
    for (int s = 32; s > 0; s >>= 1) {
        tl += __shfl_down(tl, s);
        c  += __shfl_down(c, s);
    }
    __shared__ float sb[8];
    const int lane = threadIdx.x & 63, w = threadIdx.x >> 6;
    if (lane == 0) { sb[w] = tl; sb[4 + w] = c; }
    __syncthreads();
    if (threadIdx.x == 0) {
        atomicAdd(&accum[0], sb[0] + sb[1] + sb[2] + sb[3]);
        atomicAdd(&accum[1], sb[4] + sb[5] + sb[6] + sb[7]);
    }
}

__global__ void finalize(const float* __restrict__ accum, float* __restrict__ out) {
    const float s = accum[0], c = accum[1];
    out[0] = (c > 0.0f) ? s / fmaxf(c, 1.0f) : 0.0f;
}

// ---------------------------------------------------------------------------
extern "C" void kernel_launch(void* const* d_in, const int* in_sizes, int n_in,
                              void* d_out, int out_size, void* d_ws, size_t ws_size,
                              hipStream_t stream) {
    const float* feat  = (const float*)d_in[0];
    const int* labels  = (const int*)d_in[1];
    const int* dom     = (const int*)d_in[2];
    float* out = (float*)d_out;

    char* ws = (char*)d_ws;
    // Workspace layout (bytes):
    unsigned short* G   = (unsigned short*)(ws);                 // 16,777,216
    int*      labG      = (int*)(ws + 16777216);                 //     32,768
    float*    sqG       = (float*)(ws + 16809984);               //     32,768
    unsigned* posmin    = (unsigned*)(ws + 16842752);            //     32,768
    unsigned* negmin    = (unsigned*)(ws + 16875520);            //     32,768
    unsigned* cnt       = (unsigned*)(ws + 16908288);            //  8 (cntA, cntF)
    float*    accum     = (float*)(ws + 16908296);               //  8 (sum, count)

    hipMemsetAsync(cnt, 0, 16, stream);            // counters + accum

    normalize_compact<<<B_ROWS, 256, 0, stream>>>(feat, labels, dom, G, labG,
                                                  sqG, cnt, posmin, negmin);

    // Max tiles over all nA splits: ceil(a/128)*ceil((8192-a)/128) <= 1056.
    tile_mindist<<<1056, 256, 0, stream>>>(G, labG, sqG, cnt, posmin, negmin);

    reduce_loss<<<B_ROWS / 256, 256, 0, stream>>>(posmin, negmin, accum);
    finalize<<<1, 1, 0, stream>>>(accum, out);
}